// Round 7
// baseline (1144.547 us; speedup 1.0000x reference)
//
#include <hip/hip_runtime.h>
#include <hip/hip_fp16.h>

#define NH 4     // heads
#define CH 64    // channels/head

// ---------------- encoder: h = relu(x @ W + b); x:[N,8], W:[8,64] ----------------
__global__ void encoder_kernel(const float* __restrict__ x, const float* __restrict__ W,
                               const float* __restrict__ b, float* __restrict__ h, int N) {
  int idx = blockIdx.x * blockDim.x + threadIdx.x;
  if (idx >= N * 64) return;
  int n = idx >> 6, j = idx & 63;
  const float* xp = x + n * 8;
  float acc = b[j];
#pragma unroll
  for (int k = 0; k < 8; ++k) acc = fmaf(xp[k], W[k * 64 + j], acc);
  h[idx] = fmaxf(acc, 0.0f);
}

// ---------------- xl = h@Wl + bl, xr = h@Wr + br; both stored fp16 ----------------
template <int K>
__global__ void lin_lr_kernel(const float* __restrict__ h,
                              const float* __restrict__ Wl, const float* __restrict__ bl,
                              const float* __restrict__ Wr, const float* __restrict__ br,
                              __half* __restrict__ xl, __half* __restrict__ xr, int N) {
  __shared__ float hs[8][K];
  int n0 = blockIdx.x * 8;
  int j = threadIdx.x;  // output column
  int nmax = N - n0; if (nmax > 8) nmax = 8;
  for (int idx = j; idx < nmax * K; idx += 256) {
    int m = idx / K, k = idx % K;
    hs[m][k] = h[(size_t)(n0 + m) * K + k];
  }
  __syncthreads();
  float accl[8], accr[8];
  float bjl = bl[j], bjr = br[j];
#pragma unroll
  for (int m = 0; m < 8; ++m) { accl[m] = bjl; accr[m] = bjr; }
  for (int k = 0; k < K; ++k) {
    float wl = Wl[k * 256 + j];
    float wr = Wr[k * 256 + j];
#pragma unroll
    for (int m = 0; m < 8; ++m) {
      accl[m] = fmaf(hs[m][k], wl, accl[m]);
      accr[m] = fmaf(hs[m][k], wr, accr[m]);
    }
  }
  for (int m = 0; m < nmax; ++m) {
    xl[(size_t)(n0 + m) * 256 + j] = __float2half_rn(accl[m]);
    xr[(size_t)(n0 + m) * 256 + j] = __float2half_rn(accr[m]);
  }
}

// ---------------- CSR build (counting sort by dst), fully parallel scan ----------------
__global__ void hist_kernel(const int* __restrict__ dst, int* __restrict__ deg, int E) {
  int e = blockIdx.x * blockDim.x + threadIdx.x;
  if (e < E) atomicAdd(&deg[dst[e]], 1);
}

__global__ void scan_partial_kernel(const int* __restrict__ deg, int* __restrict__ partial, int N) {
  __shared__ int sm[256];
  int t = threadIdx.x;
  int i = blockIdx.x * 256 + t;
  sm[t] = (i < N) ? deg[i] : 0;
  __syncthreads();
#pragma unroll
  for (int s = 128; s > 0; s >>= 1) {
    if (t < s) sm[t] += sm[t + s];
    __syncthreads();
  }
  if (t == 0) partial[blockIdx.x] = sm[0];
}

__global__ void scan_offsets_kernel(int* __restrict__ partial, int nb) {
  __shared__ int sm[256];
  int t = threadIdx.x;
  int v = (t < nb) ? partial[t] : 0;
  sm[t] = v;
  __syncthreads();
#pragma unroll
  for (int off = 1; off < 256; off <<= 1) {
    int a = (t >= off) ? sm[t - off] : 0;
    __syncthreads();
    sm[t] += a;
    __syncthreads();
  }
  if (t < nb) partial[t] = sm[t] - v;  // exclusive
}

__global__ void scan_final_kernel(const int* __restrict__ deg, const int* __restrict__ partial,
                                  int* __restrict__ rowptr, int* __restrict__ cursor, int N, int E) {
  __shared__ int sm[256];
  int t = threadIdx.x;
  int i = blockIdx.x * 256 + t;
  int v = (i < N) ? deg[i] : 0;
  sm[t] = v;
  __syncthreads();
#pragma unroll
  for (int off = 1; off < 256; off <<= 1) {
    int a = (t >= off) ? sm[t - off] : 0;
    __syncthreads();
    sm[t] += a;
    __syncthreads();
  }
  if (i < N) {
    int ex = partial[blockIdx.x] + sm[t] - v;
    rowptr[i] = ex;
    cursor[i] = ex;
  }
  if (i == 0) rowptr[N] = E;
}

__global__ void scatter_build_kernel(const int* __restrict__ src, const int* __restrict__ dst,
                                     const float* __restrict__ ea, int* __restrict__ cursor,
                                     int* __restrict__ srcs, float* __restrict__ eas, int E) {
  int e = blockIdx.x * blockDim.x + threadIdx.x;
  if (e >= E) return;
  int d = dst[e];
  int pos = atomicAdd(&cursor[d], 1);
  srcs[pos] = src[e];
  eas[pos] = ea[e];
}

// ---------------- fused GATv2: 2 edges/gather-inst + 2-deep pipelined gathers --------
// One wave per node. fp16 xl rows = 512B; one dwordx4/lane x 64 lanes = 1024B = TWO
// rows: lanes 0..31 edge A, lanes 32..63 edge B; lane lq=lane&31 holds channels
// 8lq..8lq+7 (head = lq>>3). Per pair: 1 gather inst, 3 shfls, 1 exp.
// NEW (R7): the pair batches (4 pairs = 8 edges) are software-pipelined 2 deep with
// a 3-buffer rotation: while batch k is processed, k+1 and k+2 are in flight. All
// loop/guard conditions are wave-uniform (beg/end uniform) -> no divergence; buffers
// are named registers (static indexing, no scratch).
__device__ __forceinline__ void unpack8(const uint4 r, float o[8]) {
  const __half2* hp = reinterpret_cast<const __half2*>(&r);
#pragma unroll
  for (int k = 0; k < 4; ++k) {
    float2 f = __half22float2(hp[k]);
    o[2 * k] = f.x; o[2 * k + 1] = f.y;
  }
}

__device__ __forceinline__ void pair_accum(const uint4 raw, const float eav, const float mask,
                                           const float xr8[8], const float We8[8], const float at8[8],
                                           float acc[8], float& den) {
  float xlv[8];
  unpack8(raw, xlv);
  float p = 0.f;
#pragma unroll
  for (int c = 0; c < 8; ++c) {
    float v = fmaf(eav, We8[c], xlv[c] + xr8[c]);
    v = (v >= 0.f) ? v : 0.2f * v;
    p = fmaf(v, at8[c], p);
  }
  p += __shfl_xor(p, 1, 64);
  p += __shfl_xor(p, 2, 64);
  p += __shfl_xor(p, 4, 64);   // 8-lane head group now holds alpha for its edge
  float ex = __expf(p) * mask;
  den += ex;
#pragma unroll
  for (int c = 0; c < 8; ++c) acc[c] = fmaf(ex, xlv[c], acc[c]);
}

// load batch kb (pairs [4kb,4kb+cnt)) into named buffer regs; cnt is wave-uniform
#define LOADB(R0, R1, R2, R3, F0, F1, F2, F3, kb)                                   \
  {                                                                                 \
    int pb_ = (kb) * 4;                                                             \
    int cnt_ = np - pb_; if (cnt_ > 4) cnt_ = 4;                                    \
    int ib_ = beg + 2 * pb_;                                                        \
    if (cnt_ > 0) { int s0_ = srcs[ib_],     s1_ = srcs[ib_ + 1];                   \
      F0 = lo ? eas[ib_]     : eas[ib_ + 1];                                        \
      R0 = xlh8[(size_t)(lo ? s0_ : s1_) * 32 + lq]; }                              \
    if (cnt_ > 1) { int s0_ = srcs[ib_ + 2], s1_ = srcs[ib_ + 3];                   \
      F1 = lo ? eas[ib_ + 2] : eas[ib_ + 3];                                        \
      R1 = xlh8[(size_t)(lo ? s0_ : s1_) * 32 + lq]; }                              \
    if (cnt_ > 2) { int s0_ = srcs[ib_ + 4], s1_ = srcs[ib_ + 5];                   \
      F2 = lo ? eas[ib_ + 4] : eas[ib_ + 5];                                        \
      R2 = xlh8[(size_t)(lo ? s0_ : s1_) * 32 + lq]; }                              \
    if (cnt_ > 3) { int s0_ = srcs[ib_ + 6], s1_ = srcs[ib_ + 7];                   \
      F3 = lo ? eas[ib_ + 6] : eas[ib_ + 7];                                        \
      R3 = xlh8[(size_t)(lo ? s0_ : s1_) * 32 + lq]; }                              \
  }

#define PROCB(R0, R1, R2, R3, F0, F1, F2, F3, kb)                                   \
  {                                                                                 \
    int pb_ = (kb) * 4;                                                             \
    int cnt_ = np - pb_; if (cnt_ > 4) cnt_ = 4;                                    \
    if (cnt_ > 0) pair_accum(R0, F0, 1.f, xr8, We8, at8, acc, den);                 \
    if (cnt_ > 1) pair_accum(R1, F1, 1.f, xr8, We8, at8, acc, den);                 \
    if (cnt_ > 2) pair_accum(R2, F2, 1.f, xr8, We8, at8, acc, den);                 \
    if (cnt_ > 3) pair_accum(R3, F3, 1.f, xr8, We8, at8, acc, den);                 \
  }

template <bool POOL>
__global__ __launch_bounds__(256)
void gat_aggregate_kernel(const int* __restrict__ rowptr,
                          const int* __restrict__ srcs,
                          const float* __restrict__ eas,
                          const __half* __restrict__ xl,
                          const __half* __restrict__ xr,
                          const float* __restrict__ We,
                          const float* __restrict__ att,
                          const float* __restrict__ bias,
                          float* __restrict__ out,
                          const int* __restrict__ batch,
                          float* __restrict__ sums,
                          float* __restrict__ cnt,
                          int N) {
  int d = (int)((blockIdx.x * (size_t)blockDim.x + threadIdx.x) >> 6);
  int lane = threadIdx.x & 63;
  if (d >= N) return;
  int lq = lane & 31;          // 16B-chunk index within a row
  bool lo = (lane < 32);
  const uint4* xlh8 = (const uint4*)xl;
  const uint4* xrh8 = (const uint4*)xr;
  float xr8[8];
  { uint4 r = xrh8[(size_t)d * 32 + lq]; unpack8(r, xr8); }
  float We8[8], at8[8];
#pragma unroll
  for (int k = 0; k < 8; ++k) { We8[k] = We[lq * 8 + k]; at8[k] = att[lq * 8 + k]; }
  int beg = rowptr[d], end = rowptr[d + 1];
  float acc[8];
#pragma unroll
  for (int c = 0; c < 8; ++c) acc[c] = 0.f;
  float den = 0.f;
  int np = (end - beg) >> 1;     // full pairs
  int nbat = (np + 3) >> 2;      // 4-pair batches

  // 3-buffer rotation, 2-deep prefetch
  uint4 a0 = {}, a1 = {}, a2 = {}, a3 = {};
  uint4 b0 = {}, b1 = {}, b2 = {}, b3 = {};
  uint4 c0_ = {}, c1_ = {}, c2_ = {}, c3_ = {};
  float fa0 = 0.f, fa1 = 0.f, fa2 = 0.f, fa3 = 0.f;
  float fb0 = 0.f, fb1 = 0.f, fb2 = 0.f, fb3 = 0.f;
  float fc0 = 0.f, fc1 = 0.f, fc2 = 0.f, fc3 = 0.f;

  LOADB(a0, a1, a2, a3, fa0, fa1, fa2, fa3, 0);
  LOADB(b0, b1, b2, b3, fb0, fb1, fb2, fb3, 1);
  for (int kb = 0; kb < nbat; kb += 3) {
    LOADB(c0_, c1_, c2_, c3_, fc0, fc1, fc2, fc3, kb + 2);
    PROCB(a0, a1, a2, a3, fa0, fa1, fa2, fa3, kb);
    LOADB(a0, a1, a2, a3, fa0, fa1, fa2, fa3, kb + 3);
    PROCB(b0, b1, b2, b3, fb0, fb1, fb2, fb3, kb + 1);
    LOADB(b0, b1, b2, b3, fb0, fb1, fb2, fb3, kb + 4);
    PROCB(c0_, c1_, c2_, c3_, fc0, fc1, fc2, fc3, kb + 2);
  }
  if ((end - beg) & 1) {         // odd tail: both halves load the edge, hi half masked
    int s0 = srcs[end - 1];
    uint4 r0 = xlh8[(size_t)s0 * 32 + lq];
    float f0 = eas[end - 1];
    pair_accum(r0, f0, lo ? 1.f : 0.f, xr8, We8, at8, acc, den);
  }
  // combine the two half-wave accumulators
  den += __shfl_xor(den, 32, 64);
#pragma unroll
  for (int c = 0; c < 8; ++c) acc[c] += __shfl_xor(acc[c], 32, 64);
  float inv = 1.f / (den + 1e-16f);
  int half = lane >> 5;
  float o0 = half ? acc[4] : acc[0];
  float o1 = half ? acc[5] : acc[1];
  float o2 = half ? acc[6] : acc[2];
  float o3 = half ? acc[7] : acc[3];
  float4 b4 = ((const float4*)bias)[lq * 2 + half];
  float4 o;
  o.x = fmaxf(fmaf(o0, inv, b4.x), 0.f);
  o.y = fmaxf(fmaf(o1, inv, b4.y), 0.f);
  o.z = fmaxf(fmaf(o2, inv, b4.z), 0.f);
  o.w = fmaxf(fmaf(o3, inv, b4.w), 0.f);
  if (POOL) {
    int g = batch[d];
    float* sg = sums + (size_t)g * 256 + lq * 8 + half * 4;
    atomicAdd(sg + 0, o.x);
    atomicAdd(sg + 1, o.y);
    atomicAdd(sg + 2, o.z);
    atomicAdd(sg + 3, o.w);
    if (lane == 0) atomicAdd(&cnt[g], 1.0f);
  } else {
    ((float4*)out)[(size_t)d * 64 + lq * 2 + half] = o;
  }
}

// ---------------- per-graph MLP head ----------------
__global__ void mlp_kernel(const float* __restrict__ sums, const float* __restrict__ cnt,
                           const float* __restrict__ p1W, const float* __restrict__ p1b,
                           const float* __restrict__ lng, const float* __restrict__ lnb,
                           const float* __restrict__ p2W, const float* __restrict__ p2b,
                           float* __restrict__ outp, int G) {
  __shared__ float p[256];
  __shared__ float z[128];
  __shared__ float wsum[2];
  __shared__ float wsum2[2];
  int g = blockIdx.x;
  int t = threadIdx.x;  // 0..127
  float c = fmaxf(cnt[g], 1.0f);
  p[t] = sums[(size_t)g * 256 + t] / c;
  p[t + 128] = sums[(size_t)g * 256 + t + 128] / c;
  __syncthreads();
  float acc = p1b[t];
  for (int k = 0; k < 256; ++k) acc = fmaf(p[k], p1W[k * 128 + t], acc);
  float v = acc;
#pragma unroll
  for (int off = 32; off > 0; off >>= 1) v += __shfl_xor(v, off, 64);
  if ((t & 63) == 0) wsum[t >> 6] = v;
  __syncthreads();
  float mu = (wsum[0] + wsum[1]) * (1.0f / 128.0f);
  float dv = acc - mu;
  float vv = dv * dv;
#pragma unroll
  for (int off = 32; off > 0; off >>= 1) vv += __shfl_xor(vv, off, 64);
  if ((t & 63) == 0) wsum2[t >> 6] = vv;
  __syncthreads();
  float var = (wsum2[0] + wsum2[1]) * (1.0f / 128.0f);
  float zv = dv * rsqrtf(var + 1e-5f) * lng[t] + lnb[t];
  z[t] = fmaxf(zv, 0.0f);
  __syncthreads();
  if (t < 64) {
    float o = p2b[t];
    for (int k = 0; k < 128; ++k) o = fmaf(z[k], p2W[k * 64 + t], o);
    outp[(size_t)g * 64 + t] = fmaxf(o, 0.0f);
  }
}

extern "C" void kernel_launch(void* const* d_in, const int* in_sizes, int n_in,
                              void* d_out, int out_size, void* d_ws, size_t ws_size,
                              hipStream_t stream) {
  const float* x      = (const float*)d_in[0];
  const int*   ei     = (const int*)d_in[1];
  const float* ea     = (const float*)d_in[2];
  const int*   batch  = (const int*)d_in[3];
  const float* enc_W  = (const float*)d_in[4];
  const float* enc_b  = (const float*)d_in[5];
  const float* Wl1    = (const float*)d_in[6];
  const float* bl1    = (const float*)d_in[7];
  const float* Wr1    = (const float*)d_in[8];
  const float* br1    = (const float*)d_in[9];
  const float* We1    = (const float*)d_in[10];
  const float* att1   = (const float*)d_in[11];
  const float* bias1  = (const float*)d_in[12];
  const float* Wl2    = (const float*)d_in[13];
  const float* bl2    = (const float*)d_in[14];
  const float* Wr2    = (const float*)d_in[15];
  const float* br2    = (const float*)d_in[16];
  const float* We2    = (const float*)d_in[17];
  const float* att2   = (const float*)d_in[18];
  const float* bias2  = (const float*)d_in[19];
  const float* p1W    = (const float*)d_in[20];
  const float* p1b    = (const float*)d_in[21];
  const float* lng    = (const float*)d_in[22];
  const float* lnb    = (const float*)d_in[23];
  const float* p2W    = (const float*)d_in[24];
  const float* p2b    = (const float*)d_in[25];
  float* outp = (float*)d_out;

  int N = in_sizes[0] / 8;
  int E = in_sizes[2];
  int G = out_size / 64;
  const int* src = ei;
  const int* dst = ei + E;
  int nb = (N + 255) / 256;   // scan blocks (<=256 supported; N=50000 -> 196)

  // ---- workspace layout (~120MB, below the proven 173MB footprint) ----
  float* ws      = (float*)d_ws;
  float* h0      = ws;                          // N*64 f32
  __half* xlh    = (__half*)(h0 + (size_t)N * 64);           // N*256 fp16
  __half* xrh    = (__half*)((float*)xlh + (size_t)N * 128); // N*256 fp16
  float* B2      = (float*)xrh + (size_t)N * 128;            // N*256 f32 (layer1 out)
  float* eas     = B2     + (size_t)N * 256;    // E floats (sorted edge attr)
  float* sums    = eas    + (size_t)E;          // G*256
  float* cnt     = sums   + (size_t)G * 256;    // G
  int*   srcs    = (int*)(cnt + G);             // E ints (sorted src)
  int*   rowptr  = srcs + (size_t)E;            // N+1
  int*   cursor  = rowptr + (size_t)(N + 1);    // N (doubles as deg histogram)
  int*   partial = cursor + (size_t)N;          // nb

  // encoder
  encoder_kernel<<<(N * 64 + 255) / 256, 256, 0, stream>>>(x, enc_W, enc_b, h0, N);

  // CSR build (shared by both layers — dst is static)
  hipMemsetAsync(cursor, 0, (size_t)N * sizeof(int), stream);
  hist_kernel<<<(E + 255) / 256, 256, 0, stream>>>(dst, cursor, E);
  scan_partial_kernel<<<nb, 256, 0, stream>>>(cursor, partial, N);
  scan_offsets_kernel<<<1, 256, 0, stream>>>(partial, nb);
  scan_final_kernel<<<nb, 256, 0, stream>>>(cursor, partial, rowptr, cursor, N, E);
  scatter_build_kernel<<<(E + 255) / 256, 256, 0, stream>>>(src, dst, ea, cursor, srcs, eas, E);

  // GAT layer 1 (K=64): h0 -> B2
  lin_lr_kernel<64><<<(N + 7) / 8, 256, 0, stream>>>(h0, Wl1, bl1, Wr1, br1, xlh, xrh, N);
  gat_aggregate_kernel<false><<<(N + 3) / 4, 256, 0, stream>>>(
      rowptr, srcs, eas, xlh, xrh, We1, att1, bias1, B2, nullptr, nullptr, nullptr, N);

  // GAT layer 2 (K=256): B2 -> pooled sums directly
  lin_lr_kernel<256><<<(N + 7) / 8, 256, 0, stream>>>(B2, Wl2, bl2, Wr2, br2, xlh, xrh, N);
  hipMemsetAsync(sums, 0, ((size_t)G * 256 + G) * sizeof(float), stream);
  gat_aggregate_kernel<true><<<(N + 3) / 4, 256, 0, stream>>>(
      rowptr, srcs, eas, xlh, xrh, We2, att2, bias2, nullptr, batch, sums, cnt, N);

  // per-graph MLP
  mlp_kernel<<<G, 128, 0, stream>>>(sums, cnt, p1W, p1b, lng, lnb, p2W, p2b, outp, G);
}

// Round 9
// 1103.686 us; speedup vs baseline: 1.0370x; 1.0370x over previous
//
#include <hip/hip_runtime.h>
#include <hip/hip_fp16.h>

#define NH 4     // heads
#define CH 64    // channels/head
#define CHUNK 8  // edges staged per chunk = 4 pair-loads of 1KB -> 4KB LDS

// ---------------- encoder: h = relu(x @ W + b); x:[N,8], W:[8,64] ----------------
__global__ void encoder_kernel(const float* __restrict__ x, const float* __restrict__ W,
                               const float* __restrict__ b, float* __restrict__ h, int N) {
  int idx = blockIdx.x * blockDim.x + threadIdx.x;
  if (idx >= N * 64) return;
  int n = idx >> 6, j = idx & 63;
  const float* xp = x + n * 8;
  float acc = b[j];
#pragma unroll
  for (int k = 0; k < 8; ++k) acc = fmaf(xp[k], W[k * 64 + j], acc);
  h[idx] = fmaxf(acc, 0.0f);
}

// ---------------- xl = h@Wl + bl, xr = h@Wr + br; both stored fp16 ----------------
template <int K>
__global__ void lin_lr_kernel(const float* __restrict__ h,
                              const float* __restrict__ Wl, const float* __restrict__ bl,
                              const float* __restrict__ Wr, const float* __restrict__ br,
                              __half* __restrict__ xl, __half* __restrict__ xr, int N) {
  __shared__ float hs[8][K];
  int n0 = blockIdx.x * 8;
  int j = threadIdx.x;  // output column
  int nmax = N - n0; if (nmax > 8) nmax = 8;
  for (int idx = j; idx < nmax * K; idx += 256) {
    int m = idx / K, k = idx % K;
    hs[m][k] = h[(size_t)(n0 + m) * K + k];
  }
  __syncthreads();
  float accl[8], accr[8];
  float bjl = bl[j], bjr = br[j];
#pragma unroll
  for (int m = 0; m < 8; ++m) { accl[m] = bjl; accr[m] = bjr; }
  for (int k = 0; k < K; ++k) {
    float wl = Wl[k * 256 + j];
    float wr = Wr[k * 256 + j];
#pragma unroll
    for (int m = 0; m < 8; ++m) {
      accl[m] = fmaf(hs[m][k], wl, accl[m]);
      accr[m] = fmaf(hs[m][k], wr, accr[m]);
    }
  }
  for (int m = 0; m < nmax; ++m) {
    xl[(size_t)(n0 + m) * 256 + j] = __float2half_rn(accl[m]);
    xr[(size_t)(n0 + m) * 256 + j] = __float2half_rn(accr[m]);
  }
}

// ---------------- CSR build (counting sort by dst), fully parallel scan ----------------
__global__ void hist_kernel(const int* __restrict__ dst, int* __restrict__ deg, int E) {
  int e = blockIdx.x * blockDim.x + threadIdx.x;
  if (e < E) atomicAdd(&deg[dst[e]], 1);
}

__global__ void scan_partial_kernel(const int* __restrict__ deg, int* __restrict__ partial, int N) {
  __shared__ int sm[256];
  int t = threadIdx.x;
  int i = blockIdx.x * 256 + t;
  sm[t] = (i < N) ? deg[i] : 0;
  __syncthreads();
#pragma unroll
  for (int s = 128; s > 0; s >>= 1) {
    if (t < s) sm[t] += sm[t + s];
    __syncthreads();
  }
  if (t == 0) partial[blockIdx.x] = sm[0];
}

__global__ void scan_offsets_kernel(int* __restrict__ partial, int nb) {
  __shared__ int sm[256];
  int t = threadIdx.x;
  int v = (t < nb) ? partial[t] : 0;
  sm[t] = v;
  __syncthreads();
#pragma unroll
  for (int off = 1; off < 256; off <<= 1) {
    int a = (t >= off) ? sm[t - off] : 0;
    __syncthreads();
    sm[t] += a;
    __syncthreads();
  }
  if (t < nb) partial[t] = sm[t] - v;  // exclusive
}

__global__ void scan_final_kernel(const int* __restrict__ deg, const int* __restrict__ partial,
                                  int* __restrict__ rowptr, int* __restrict__ cursor, int N, int E) {
  __shared__ int sm[256];
  int t = threadIdx.x;
  int i = blockIdx.x * 256 + t;
  int v = (i < N) ? deg[i] : 0;
  sm[t] = v;
  __syncthreads();
#pragma unroll
  for (int off = 1; off < 256; off <<= 1) {
    int a = (t >= off) ? sm[t - off] : 0;
    __syncthreads();
    sm[t] += a;
    __syncthreads();
  }
  if (i < N) {
    int ex = partial[blockIdx.x] + sm[t] - v;
    rowptr[i] = ex;
    cursor[i] = ex;
  }
  if (i == 0) rowptr[N] = E;
}

__global__ void scatter_build_kernel(const int* __restrict__ src, const int* __restrict__ dst,
                                     const float* __restrict__ ea, int* __restrict__ cursor,
                                     int* __restrict__ srcs, float* __restrict__ eas, int E) {
  int e = blockIdx.x * blockDim.x + threadIdx.x;
  if (e >= E) return;
  int d = dst[e];
  int pos = atomicAdd(&cursor[d], 1);
  srcs[pos] = src[e];
  eas[pos] = ea[e];
}

// ---------------- fused GATv2: LDS-staged gather via global_load_lds ----------------
// One wave per node, R6 pair math (2 edge rows per 1KB load: lanes 0..31 edge A,
// 32..63 edge B; lane lq=lane&31 holds channels 8lq..8lq+7, head=lq>>3).
// R8/R9: gathers go global->LDS with __builtin_amdgcn_global_load_lds (per-lane
// global src addr, wave-uniform LDS dst + lane*16 -- the m104/m173 contract).
// Staging holds NO destination VGPRs, so chunk k+1 (4 insts = 8 rows = 4KB) stays
// in flight across the processing of chunk k, gated by counted s_waitcnt vmcnt(4)
// (T4 discipline; over-waits on interleaved meta loads, never under-waits).
// Per-wave LDS: 2 x 4KB double buffer; block (4 waves) = 32KB -> 5 blocks/CU.
__device__ __forceinline__ void gload_lds16(const void* g, void* l) {
  __builtin_amdgcn_global_load_lds(
      (const __attribute__((address_space(1))) void*)g,
      (__attribute__((address_space(3))) void*)l, 16, 0, 0);
}

__device__ __forceinline__ void unpack8(const uint4 r, float o[8]) {
  const __half2* hp = reinterpret_cast<const __half2*>(&r);
#pragma unroll
  for (int k = 0; k < 4; ++k) {
    float2 f = __half22float2(hp[k]);
    o[2 * k] = f.x; o[2 * k + 1] = f.y;
  }
}

__device__ __forceinline__ void pair_accum(const uint4 raw, const float eav, const float mask,
                                           const float xr8[8], const float We8[8], const float at8[8],
                                           float acc[8], float& den) {
  float xlv[8];
  unpack8(raw, xlv);
  float p = 0.f;
#pragma unroll
  for (int c = 0; c < 8; ++c) {
    float v = fmaf(eav, We8[c], xlv[c] + xr8[c]);
    v = (v >= 0.f) ? v : 0.2f * v;
    p = fmaf(v, at8[c], p);
  }
  p += __shfl_xor(p, 1, 64);
  p += __shfl_xor(p, 2, 64);
  p += __shfl_xor(p, 4, 64);   // 8-lane head group holds alpha for its edge
  float ex = __expf(p) * mask;
  den += ex;
#pragma unroll
  for (int c = 0; c < 8; ++c) acc[c] = fmaf(ex, xlv[c], acc[c]);
}

template <bool POOL>
__global__ __launch_bounds__(256)
void gat_aggregate_kernel(const int* __restrict__ rowptr,
                          const int* __restrict__ srcs,
                          const float* __restrict__ eas,
                          const __half* __restrict__ xl,
                          const __half* __restrict__ xr,
                          const float* __restrict__ We,
                          const float* __restrict__ att,
                          const float* __restrict__ bias,
                          float* __restrict__ out,
                          const int* __restrict__ batch,
                          float* __restrict__ sums,
                          float* __restrict__ cnt,
                          int N) {
  __shared__ __align__(16) char smem[4 * 2 * 4096];   // 4 waves x dbuf x 4KB
  int d = (int)((blockIdx.x * (size_t)blockDim.x + threadIdx.x) >> 6);
  int lane = threadIdx.x & 63;
  if (d >= N) return;
  int w = threadIdx.x >> 6;
  char* mybuf = smem + w * 8192;
  int lq = lane & 31;
  bool lo = (lane < 32);
  const uint4* xrh8 = (const uint4*)xr;
  float xr8[8];
  { uint4 r = xrh8[(size_t)d * 32 + lq]; unpack8(r, xr8); }
  float We8[8], at8[8];
#pragma unroll
  for (int k = 0; k < 8; ++k) { We8[k] = We[lq * 8 + k]; at8[k] = att[lq * 8 + k]; }
  int beg = rowptr[d], end = rowptr[d + 1];
  int deg = end - beg;
  float acc[8];
#pragma unroll
  for (int c = 0; c < 8; ++c) acc[c] = 0.f;
  float den = 0.f;

  if (deg > 0) {
    int nch = (deg + CHUNK - 1) / CHUNK;
    int dm1 = deg - 1;
    int s_[8]; float e_[8];
    // ---- prologue: meta(0), stage(0), meta for chunk 1 + eas(0) ----
#pragma unroll
    for (int j = 0; j < 8; ++j) { int jj = j < dm1 ? j : dm1; s_[j] = srcs[beg + jj]; }
    {
      char* b0 = mybuf;   // buf 0
#pragma unroll
      for (int p = 0; p < 4; ++p) {
        int sA = s_[2 * p], sB = s_[2 * p + 1];
        const char* g = (const char*)xl + (((size_t)(lo ? sA : sB)) << 9) + ((size_t)lq << 4);
        gload_lds16(g, b0 + p * 1024);
      }
    }
#pragma unroll
    for (int j = 0; j < 8; ++j) {
      int j1 = (8 + j) < dm1 ? (8 + j) : dm1;
      s_[j] = srcs[beg + j1];
      int j0 = j < dm1 ? j : dm1;
      e_[j] = eas[beg + j0];
    }
    // ---- main loop over chunks ----
    for (int k = 0; k < nch; ++k) {
      int bufsel = k & 1;
      if (k + 1 < nch) {
        char* bn = mybuf + ((k + 1) & 1) * 4096;
#pragma unroll
        for (int p = 0; p < 4; ++p) {
          int sA = s_[2 * p], sB = s_[2 * p + 1];
          const char* g = (const char*)xl + (((size_t)(lo ? sA : sB)) << 9) + ((size_t)lq << 4);
          gload_lds16(g, bn + p * 1024);
        }
        asm volatile("s_waitcnt vmcnt(4)" ::: "memory");  // chunk k staged; k+1 in flight
      } else {
        asm volatile("s_waitcnt vmcnt(0)" ::: "memory");  // final chunk: drain
      }
      // process chunk k from LDS
      int c = deg - k * CHUNK; if (c > CHUNK) c = CHUNK;
      int fp = c >> 1, half = c & 1;
      const char* pb = mybuf + bufsel * 4096;
#pragma unroll
      for (int p = 0; p < 4; ++p) {
        if (p < fp || (p == fp && half)) {
          uint4 r = *(const uint4*)(pb + p * 1024 + (size_t)lane * 16);
          float f = lo ? e_[2 * p] : e_[2 * p + 1];
          float m = (p < fp) ? 1.f : (lo ? 1.f : 0.f);
          pair_accum(r, f, m, xr8, We8, at8, acc, den);
        }
      }
      // meta for next iterations (clamped; harmless cache-hit loads when past end)
#pragma unroll
      for (int j = 0; j < 8; ++j) {
        int js = (k + 2) * CHUNK + j; js = js < dm1 ? js : dm1;
        s_[j] = srcs[beg + js];
        int je = (k + 1) * CHUNK + j; je = je < dm1 ? je : dm1;
        e_[j] = eas[beg + je];
      }
    }
  }
  // combine the two half-wave accumulators
  den += __shfl_xor(den, 32, 64);
#pragma unroll
  for (int c = 0; c < 8; ++c) acc[c] += __shfl_xor(acc[c], 32, 64);
  float inv = 1.f / (den + 1e-16f);
  int half = lane >> 5;
  float o0 = half ? acc[4] : acc[0];
  float o1 = half ? acc[5] : acc[1];
  float o2 = half ? acc[6] : acc[2];
  float o3 = half ? acc[7] : acc[3];
  float4 b4 = ((const float4*)bias)[lq * 2 + half];
  float4 o;
  o.x = fmaxf(fmaf(o0, inv, b4.x), 0.f);
  o.y = fmaxf(fmaf(o1, inv, b4.y), 0.f);
  o.z = fmaxf(fmaf(o2, inv, b4.z), 0.f);
  o.w = fmaxf(fmaf(o3, inv, b4.w), 0.f);
  if (POOL) {
    int g = batch[d];
    float* sg = sums + (size_t)g * 256 + lq * 8 + half * 4;
    atomicAdd(sg + 0, o.x);
    atomicAdd(sg + 1, o.y);
    atomicAdd(sg + 2, o.z);
    atomicAdd(sg + 3, o.w);
    if (lane == 0) atomicAdd(&cnt[g], 1.0f);
  } else {
    ((float4*)out)[(size_t)d * 64 + lq * 2 + half] = o;
  }
}

// ---------------- per-graph MLP head ----------------
__global__ void mlp_kernel(const float* __restrict__ sums, const float* __restrict__ cnt,
                           const float* __restrict__ p1W, const float* __restrict__ p1b,
                           const float* __restrict__ lng, const float* __restrict__ lnb,
                           const float* __restrict__ p2W, const float* __restrict__ p2b,
                           float* __restrict__ outp, int G) {
  __shared__ float p[256];
  __shared__ float z[128];
  __shared__ float wsum[2];
  __shared__ float wsum2[2];
  int g = blockIdx.x;
  int t = threadIdx.x;  // 0..127
  float c = fmaxf(cnt[g], 1.0f);
  p[t] = sums[(size_t)g * 256 + t] / c;
  p[t + 128] = sums[(size_t)g * 256 + t + 128] / c;
  __syncthreads();
  float acc = p1b[t];
  for (int k = 0; k < 256; ++k) acc = fmaf(p[k], p1W[k * 128 + t], acc);
  float v = acc;
#pragma unroll
  for (int off = 32; off > 0; off >>= 1) v += __shfl_xor(v, off, 64);
  if ((t & 63) == 0) wsum[t >> 6] = v;
  __syncthreads();
  float mu = (wsum[0] + wsum[1]) * (1.0f / 128.0f);
  float dv = acc - mu;
  float vv = dv * dv;
#pragma unroll
  for (int off = 32; off > 0; off >>= 1) vv += __shfl_xor(vv, off, 64);
  if ((t & 63) == 0) wsum2[t >> 6] = vv;
  __syncthreads();
  float var = (wsum2[0] + wsum2[1]) * (1.0f / 128.0f);
  float zv = dv * rsqrtf(var + 1e-5f) * lng[t] + lnb[t];
  z[t] = fmaxf(zv, 0.0f);
  __syncthreads();
  if (t < 64) {
    float o = p2b[t];
    for (int k = 0; k < 128; ++k) o = fmaf(z[k], p2W[k * 64 + t], o);
    outp[(size_t)g * 64 + t] = fmaxf(o, 0.0f);
  }
}

extern "C" void kernel_launch(void* const* d_in, const int* in_sizes, int n_in,
                              void* d_out, int out_size, void* d_ws, size_t ws_size,
                              hipStream_t stream) {
  const float* x      = (const float*)d_in[0];
  const int*   ei     = (const int*)d_in[1];
  const float* ea     = (const float*)d_in[2];
  const int*   batch  = (const int*)d_in[3];
  const float* enc_W  = (const float*)d_in[4];
  const float* enc_b  = (const float*)d_in[5];
  const float* Wl1    = (const float*)d_in[6];
  const float* bl1    = (const float*)d_in[7];
  const float* Wr1    = (const float*)d_in[8];
  const float* br1    = (const float*)d_in[9];
  const float* We1    = (const float*)d_in[10];
  const float* att1   = (const float*)d_in[11];
  const float* bias1  = (const float*)d_in[12];
  const float* Wl2    = (const float*)d_in[13];
  const float* bl2    = (const float*)d_in[14];
  const float* Wr2    = (const float*)d_in[15];
  const float* br2    = (const float*)d_in[16];
  const float* We2    = (const float*)d_in[17];
  const float* att2   = (const float*)d_in[18];
  const float* bias2  = (const float*)d_in[19];
  const float* p1W    = (const float*)d_in[20];
  const float* p1b    = (const float*)d_in[21];
  const float* lng    = (const float*)d_in[22];
  const float* lnb    = (const float*)d_in[23];
  const float* p2W    = (const float*)d_in[24];
  const float* p2b    = (const float*)d_in[25];
  float* outp = (float*)d_out;

  int N = in_sizes[0] / 8;
  int E = in_sizes[2];
  int G = out_size / 64;
  const int* src = ei;
  const int* dst = ei + E;
  int nb = (N + 255) / 256;   // scan blocks (<=256 supported; N=50000 -> 196)

  // ---- workspace layout (~120MB, below the proven 173MB footprint) ----
  float* ws      = (float*)d_ws;
  float* h0      = ws;                          // N*64 f32
  __half* xlh    = (__half*)(h0 + (size_t)N * 64);           // N*256 fp16
  __half* xrh    = (__half*)((float*)xlh + (size_t)N * 128); // N*256 fp16
  float* B2      = (float*)xrh + (size_t)N * 128;            // N*256 f32 (layer1 out)
  float* eas     = B2     + (size_t)N * 256;    // E floats (sorted edge attr)
  float* sums    = eas    + (size_t)E;          // G*256
  float* cnt     = sums   + (size_t)G * 256;    // G
  int*   srcs    = (int*)(cnt + G);             // E ints (sorted src)
  int*   rowptr  = srcs + (size_t)E;            // N+1
  int*   cursor  = rowptr + (size_t)(N + 1);    // N (doubles as deg histogram)
  int*   partial = cursor + (size_t)N;          // nb

  // encoder
  encoder_kernel<<<(N * 64 + 255) / 256, 256, 0, stream>>>(x, enc_W, enc_b, h0, N);

  // CSR build (shared by both layers — dst is static)
  hipMemsetAsync(cursor, 0, (size_t)N * sizeof(int), stream);
  hist_kernel<<<(E + 255) / 256, 256, 0, stream>>>(dst, cursor, E);
  scan_partial_kernel<<<nb, 256, 0, stream>>>(cursor, partial, N);
  scan_offsets_kernel<<<1, 256, 0, stream>>>(partial, nb);
  scan_final_kernel<<<nb, 256, 0, stream>>>(cursor, partial, rowptr, cursor, N, E);
  scatter_build_kernel<<<(E + 255) / 256, 256, 0, stream>>>(src, dst, ea, cursor, srcs, eas, E);

  // GAT layer 1 (K=64): h0 -> B2
  lin_lr_kernel<64><<<(N + 7) / 8, 256, 0, stream>>>(h0, Wl1, bl1, Wr1, br1, xlh, xrh, N);
  gat_aggregate_kernel<false><<<(N + 3) / 4, 256, 0, stream>>>(
      rowptr, srcs, eas, xlh, xrh, We1, att1, bias1, B2, nullptr, nullptr, nullptr, N);

  // GAT layer 2 (K=256): B2 -> pooled sums directly
  lin_lr_kernel<256><<<(N + 7) / 8, 256, 0, stream>>>(B2, Wl2, bl2, Wr2, br2, xlh, xrh, N);
  hipMemsetAsync(sums, 0, ((size_t)G * 256 + G) * sizeof(float), stream);
  gat_aggregate_kernel<true><<<(N + 3) / 4, 256, 0, stream>>>(
      rowptr, srcs, eas, xlh, xrh, We2, att2, bias2, nullptr, batch, sums, cnt, N);

  // per-graph MLP
  mlp_kernel<<<G, 128, 0, stream>>>(sums, cnt, p1W, p1b, lng, lnb, p2W, p2b, outp, G);
}